// Round 3
// baseline (284.691 us; speedup 1.0000x reference)
//
#include <hip/hip_runtime.h>

// Problem: B=16, T=128, H=56, W=56, C=8  (fp32)
//   active_sum[b,c] = sum_{t<len,h,w} cam ;  total_sum = sum over all t
//   out[b] = mean_c huber(count, active) + mean_c huber(0, total-active) + 0.1*ttv
//   ttv = sum_{t>=1} |masked[t]-masked[t-1]|  (masked = cam * (t<len))
//
// HBM-bound: 205.5 MB read once -> ~33 us floor. Per-thread t-walk keeps the
// previous t-slice in registers (temporal diff costs no extra traffic).
// R3: no memset, no global atomics — per-block partials to private ws slots,
// deterministic sum in the final kernel. 2 dispatches total.

#define NB 16
#define NT 128
#define NC 8
#define I4PBT 6272        // H*W*C/4
#define TCHUNKS 4
#define TCH 32            // NT / TCHUNKS
#define BLK 256
#define BLKS_PER_BT 25    // ceil(6272/256)
#define NBLOCKS (NB * TCHUNKS * BLKS_PER_BT)   // 1600
#define PSTRIDE 20        // floats per block partial slot (17 used, padded)

// ws: block blk writes ws[blk*PSTRIDE + 0..7]=active[c], +8..15=total[c], +16=ttv

__global__ void __launch_bounds__(BLK)
ttv_reduce_kernel(const float* __restrict__ cam, const int* __restrict__ length,
                  float* __restrict__ ws) {
    const int blk = blockIdx.x;
    const int bt  = blk / BLKS_PER_BT;
    const int i4b = blk - bt * BLKS_PER_BT;
    const int b   = bt >> 2;
    const int tch = bt & 3;
    const int i4  = i4b * BLK + threadIdx.x;
    const bool live = (i4 < I4PBT);
    const int len = length[b];
    const int t0  = tch * TCH;

    float aA0=0.f,aA1=0.f,aA2=0.f,aA3=0.f;
    float aT0=0.f,aT1=0.f,aT2=0.f,aT3=0.f;
    float ttv = 0.f;

    if (live) {
        const float4* base = (const float4*)cam + (size_t)b * (size_t)(NT * I4PBT) + i4;
        float p0=0.f,p1=0.f,p2=0.f,p3=0.f;
        if (t0 > 0 && (t0 - 1) < len) {
            float4 v = base[(size_t)(t0 - 1) * I4PBT];
            p0 = v.x; p1 = v.y; p2 = v.z; p3 = v.w;
        }
        for (int tt = 0; tt < TCH; tt += 4) {
            float4 v[4];
            #pragma unroll
            for (int j = 0; j < 4; ++j)
                v[j] = base[(size_t)(t0 + tt + j) * I4PBT];
            #pragma unroll
            for (int j = 0; j < 4; ++j) {
                const int t = t0 + tt + j;
                aT0 += v[j].x; aT1 += v[j].y; aT2 += v[j].z; aT3 += v[j].w;
                float m0, m1, m2, m3;
                if (t < len) { m0 = v[j].x; m1 = v[j].y; m2 = v[j].z; m3 = v[j].w; }
                else         { m0 = 0.f;    m1 = 0.f;    m2 = 0.f;    m3 = 0.f;    }
                aA0 += m0; aA1 += m1; aA2 += m2; aA3 += m3;
                const float d = fabsf(m0 - p0) + fabsf(m1 - p1)
                              + fabsf(m2 - p2) + fabsf(m3 - p3);
                if (t > 0) ttv += d;
                p0 = m0; p1 = m1; p2 = m2; p3 = m3;
            }
        }
    }

    // Butterfly reduce; XOR masks >=2 preserve lane parity (= channel half).
    #pragma unroll
    for (int m = 32; m >= 2; m >>= 1) {
        aA0 += __shfl_xor(aA0, m); aA1 += __shfl_xor(aA1, m);
        aA2 += __shfl_xor(aA2, m); aA3 += __shfl_xor(aA3, m);
        aT0 += __shfl_xor(aT0, m); aT1 += __shfl_xor(aT1, m);
        aT2 += __shfl_xor(aT2, m); aT3 += __shfl_xor(aT3, m);
        ttv += __shfl_xor(ttv, m);
    }
    ttv += __shfl_xor(ttv, 1);

    // Intra-block combine via LDS (4 waves), no atomics.
    __shared__ float lA[4][NC], lT[4][NC], lttv[4];
    const int wave = threadIdx.x >> 6;
    const int lane = threadIdx.x & 63;
    if (lane < 2) {                      // lane0: ch 0-3, lane1: ch 4-7
        const int cb = lane << 2;
        lA[wave][cb+0] = aA0; lA[wave][cb+1] = aA1;
        lA[wave][cb+2] = aA2; lA[wave][cb+3] = aA3;
        lT[wave][cb+0] = aT0; lT[wave][cb+1] = aT1;
        lT[wave][cb+2] = aT2; lT[wave][cb+3] = aT3;
    }
    if (lane == 0) lttv[wave] = ttv;
    __syncthreads();

    if (threadIdx.x < NC) {
        const int c = threadIdx.x;
        float sA = lA[0][c] + lA[1][c] + lA[2][c] + lA[3][c];
        float sT = lT[0][c] + lT[1][c] + lT[2][c] + lT[3][c];
        ws[blk * PSTRIDE + c]      = sA;
        ws[blk * PSTRIDE + NC + c] = sT;
    } else if (threadIdx.x == NC) {
        ws[blk * PSTRIDE + 16] = lttv[0] + lttv[1] + lttv[2] + lttv[3];
    }
}

__global__ void __launch_bounds__(BLK)
ttv_final_kernel(const float* __restrict__ count, const float* __restrict__ ws,
                 float* __restrict__ out) {
    const int tid = threadIdx.x;         // 0..255

    // ttv: sum 1600 per-block scalars across 256 threads
    float tv = 0.f;
    for (int i = tid; i < NBLOCKS; i += BLK)
        tv += ws[i * PSTRIDE + 16];
    #pragma unroll
    for (int m = 32; m >= 1; m >>= 1) tv += __shfl_xor(tv, m);
    __shared__ float wtv[4];
    const int wave = tid >> 6, lane = tid & 63;
    if (lane == 0) wtv[wave] = tv;
    __syncthreads();
    const float sttv = wtv[0] + wtv[1] + wtv[2] + wtv[3];

    if (tid < NB * NC) {
        const int b = tid >> 3;
        const int c = tid & 7;
        // sum partials from the 100 blocks (4 tch x 25 i4b) of batch b
        float a_sum = 0.f, t_sum = 0.f;
        const int blk0 = b * TCHUNKS * BLKS_PER_BT;
        for (int k = 0; k < TCHUNKS * BLKS_PER_BT; ++k) {
            a_sum += ws[(blk0 + k) * PSTRIDE + c];
            t_sum += ws[(blk0 + k) * PSTRIDE + NC + c];
        }
        const float blank = t_sum - a_sum;
        const float e1 = a_sum - count[tid];
        const float a1 = fabsf(e1);
        const float h1 = (a1 <= 1.f) ? 0.5f * e1 * e1 : a1 - 0.5f;
        const float a2 = fabsf(blank);
        const float h2 = (a2 <= 1.f) ? 0.5f * blank * blank : a2 - 0.5f;

        float h = h1 + h2;
        h += __shfl_xor(h, 4);
        h += __shfl_xor(h, 2);
        h += __shfl_xor(h, 1);
        if (c == 0) out[b] = h * 0.125f + sttv * 0.1f;
    }
}

extern "C" void kernel_launch(void* const* d_in, const int* in_sizes, int n_in,
                              void* d_out, int out_size, void* d_ws, size_t ws_size,
                              hipStream_t stream) {
    const float* cam    = (const float*)d_in[0];
    const float* count  = (const float*)d_in[1];
    const int*   length = (const int*)d_in[2];
    float* out = (float*)d_out;
    float* ws  = (float*)d_ws;

    ttv_reduce_kernel<<<NBLOCKS, BLK, 0, stream>>>(cam, length, ws);
    ttv_final_kernel<<<1, BLK, 0, stream>>>(count, ws, out);
}